// Round 7
// baseline (994.317 us; speedup 1.0000x reference)
//
#include <hip/hip_runtime.h>
#include <hip/hip_bf16.h>

using bf16 = __hip_bfloat16;
typedef short v8s __attribute__((ext_vector_type(8)));
typedef float v16f __attribute__((ext_vector_type(16)));

#define NE 8
#define NT 16384
#define ND 1024
#define NH 4096
#define CAP 2048

__device__ __forceinline__ void load_lds16(const void* g, void* s) {
  __builtin_amdgcn_global_load_lds(
      (const __attribute__((address_space(1))) unsigned int*)g,
      (__attribute__((address_space(3))) unsigned int*)s, 16, 0, 0);
}

__device__ __forceinline__ float gelu_tanh(float x) {
  float u = 0.7978845608028654f * (x + 0.044715f * x * x * x);
  float e = __expf(2.0f * u);
  float t = 1.0f - 2.0f / (e + 1.0f);
  return 0.5f * x * (1.0f + t);
}

// ---------------- fp32 -> bf16 elementwise ----------------
__global__ __launch_bounds__(256) void cvt_bf16(const float* __restrict__ s,
                                                bf16* __restrict__ d, int n) {
  for (int i = (blockIdx.x * 256 + threadIdx.x) * 4; i < n; i += gridDim.x * 1024) {
    float4 v = *(const float4*)(s + i);
    bf16 o[4];
    o[0] = __float2bfloat16(v.x); o[1] = __float2bfloat16(v.y);
    o[2] = __float2bfloat16(v.z); o[3] = __float2bfloat16(v.w);
    *(ushort4*)(d + i) = *(ushort4*)o;
  }
}

// ---------------- fp32 (R,C) -> bf16 (C,R), batched over blockIdx.z ----------
__global__ __launch_bounds__(256) void tcvt(const float* __restrict__ src,
                                            bf16* __restrict__ dst, int R, int C) {
  __shared__ float tile[32][33];
  size_t mo = (size_t)blockIdx.z * R * C;
  int c0 = blockIdx.x * 32, r0 = blockIdx.y * 32;
  int tx = threadIdx.x & 31, ty = threadIdx.x >> 5;
  for (int i = ty; i < 32; i += 8)
    tile[i][tx] = src[mo + (size_t)(r0 + i) * C + c0 + tx];
  __syncthreads();
  for (int i = ty; i < 32; i += 8)
    dst[mo + (size_t)(c0 + i) * R + r0 + tx] = __float2bfloat16(tile[tx][i]);
}

// ---------------- router: logits (fp64 accum) + softmax -> probs[E][T] ------
__global__ __launch_bounds__(256) void router_k(const float* __restrict__ x,
                                                const float* __restrict__ gate,
                                                float* __restrict__ probs) {
  int wave = threadIdx.x >> 6, lane = threadIdx.x & 63;
  int t = blockIdx.x * 4 + wave;
  const float* xr = x + (size_t)t * ND;
  double acc[NE];
#pragma unroll
  for (int e = 0; e < NE; e++) acc[e] = 0.0;
  for (int d = lane; d < ND; d += 64) {
    double xv = (double)xr[d];
    const float* g = gate + d * NE;
#pragma unroll
    for (int e = 0; e < NE; e++) acc[e] += xv * (double)g[e];
  }
#pragma unroll
  for (int e = 0; e < NE; e++) {
    double v = acc[e];
#pragma unroll
    for (int off = 32; off > 0; off >>= 1) v += __shfl_xor(v, off);
    acc[e] = v;
  }
  if (lane == 0) {
    float l[NE], m = -1e30f;
#pragma unroll
    for (int e = 0; e < NE; e++) { l[e] = (float)acc[e]; m = fmaxf(m, l[e]); }
    float p[NE], s = 0.f;
#pragma unroll
    for (int e = 0; e < NE; e++) { p[e] = expf(l[e] - m); s += p[e]; }
#pragma unroll
    for (int e = 0; e < NE; e++) probs[e * NT + t] = p[e] / s;
  }
}

// ---------------- per-expert radix select of the 2048th largest prob --------
__global__ __launch_bounds__(1024) void topk_k(const float* __restrict__ probs,
                                               unsigned* __restrict__ thr_key,
                                               int* __restrict__ needed) {
  int e = blockIdx.x;
  const float* p = probs + e * NT;
  __shared__ int hist[256];
  __shared__ unsigned s_pref;
  __shared__ int s_rank;
  unsigned prefix = 0;
  int rank = CAP;
  for (int rd = 0; rd < 4; rd++) {
    int shift = 24 - rd * 8;
    if (threadIdx.x < 256) hist[threadIdx.x] = 0;
    __syncthreads();
    unsigned mask = (rd == 0) ? 0u : (0xFFFFFFFFu << (shift + 8));
    for (int t = threadIdx.x; t < NT; t += 1024) {
      unsigned k = __float_as_uint(p[t]);
      if ((k & mask) == prefix) atomicAdd(&hist[(k >> shift) & 255], 1);
    }
    __syncthreads();
    if (threadIdx.x == 0) {
      int cum = 0, b = 255;
      for (;;) {
        int c = hist[b];
        if (cum + c >= rank || b == 0) break;
        cum += c; b--;
      }
      s_pref = prefix | ((unsigned)b << shift);
      s_rank = rank - cum;
    }
    __syncthreads();
    prefix = s_pref; rank = s_rank;
    __syncthreads();
  }
  if (threadIdx.x == 0) { thr_key[e] = prefix; needed[e] = rank; }
}

__global__ void zero_counters(int* p) {
  if (threadIdx.x < 2 * NE) p[threadIdx.x] = 0;
}

// -------- compact: block-aggregated (1 atomic/class/block) ------------------
__global__ __launch_bounds__(256) void compact_k(const float* __restrict__ probs,
                                                 const unsigned* __restrict__ thr_key,
                                                 const int* __restrict__ needed,
                                                 int* __restrict__ cnt, int* __restrict__ eqc,
                                                 int* __restrict__ tok, float* __restrict__ scr) {
  int gid = blockIdx.x * 256 + threadIdx.x;
  int e = gid >> 14, t = gid & (NT - 1);
  float pv = probs[gid];
  unsigned k = __float_as_uint(pv);
  unsigned thr = thr_key[e];
  int nd = needed[e];
  bool gt = k > thr, eq = k == thr;
  unsigned long long mgt = __ballot(gt), meq = __ballot(eq);
  int lane = threadIdx.x & 63, wv = threadIdx.x >> 6;
  __shared__ int wcnt[2][4];
  __shared__ int base[2];
  if (lane == 0) { wcnt[0][wv] = __popcll(mgt); wcnt[1][wv] = __popcll(meq); }
  __syncthreads();
  if (threadIdx.x == 0) {
    int s0 = wcnt[0][0] + wcnt[0][1] + wcnt[0][2] + wcnt[0][3];
    int s1 = wcnt[1][0] + wcnt[1][1] + wcnt[1][2] + wcnt[1][3];
    base[0] = s0 ? atomicAdd(&cnt[e], s0) : 0;
    base[1] = s1 ? atomicAdd(&eqc[e], s1) : 0;
  }
  __syncthreads();
  unsigned long long lm = (1ull << lane) - 1ull;
  if (gt) {
    int p = __popcll(mgt & lm);
    for (int w = 0; w < wv; w++) p += wcnt[0][w];
    int slot = base[0] + p;
    tok[e * CAP + slot] = t; scr[e * CAP + slot] = pv;
  } else if (eq) {
    int q = base[1] + __popcll(meq & lm);
    for (int w = 0; w < wv; w++) q += wcnt[1][w];
    if (q < nd) {
      int slot = (CAP - nd) + q;
      tok[e * CAP + slot] = t; scr[e * CAP + slot] = pv;
    }
  }
}

// === 256x256 GEMM, mfma_f32_32x32x16_bf16, 2 barriers/tile ===================
// DRAIN=0: counted vmcnt(4) gate; DRAIN=1: vmcnt(0) drain (A/B experiment).
#define BAR() __builtin_amdgcn_s_barrier()

template <int MODE, int DRAIN>
__global__ __launch_bounds__(512, 2) void gemm256(
    const bf16* __restrict__ A, int lda, const int* __restrict__ rowmap,
    const bf16* __restrict__ BT, long long bstride, int gshift,
    const float* __restrict__ bias, int bias_stride,
    int N, int K,
    bf16* __restrict__ outH, float* __restrict__ outF,
    const int* __restrict__ tok, const float* __restrict__ scr) {
  __shared__ __attribute__((aligned(16))) char A0s[32768];
  __shared__ __attribute__((aligned(16))) char A1s[32768];
  __shared__ __attribute__((aligned(16))) char B0s[32768];
  __shared__ __attribute__((aligned(16))) char B1s[32768];
  const int tid = threadIdx.x;
  const int lane = tid & 63, wv = tid >> 6;
  const int wr = wv >> 2, wc = wv & 3;             // 2x4 wave grid
  const int m0 = blockIdx.y << 8, n0 = blockIdx.x << 8;
  const int grp = m0 >> gshift;
  const bf16* Bp = BT + (size_t)grp * (size_t)bstride;
  const float* bp = bias + (size_t)grp * (size_t)bias_stride;
  const int nt = K >> 6;                           // K-tiles of 64; even, >=4

  // ---- staging (pre-swizzled global source cols, linear LDS dest) ----
  const int srow = tid >> 3;
  const int pc = tid & 7;
  const int gc = pc ^ (srow & 7);
  const bf16* srcA[4]; const bf16* srcB[4];
#pragma unroll
  for (int g = 0; g < 4; g++) {
    int am = m0 + g * 64 + srow;
    int ar = rowmap ? rowmap[am] : am;
    srcA[g] = A + (size_t)ar * lda + gc * 8;
    srcB[g] = Bp + (size_t)(n0 + g * 64 + srow) * K + gc * 8;
  }
#define STA(ARR, T, H)                                                        \
  { char* d_ = (ARR) + (H) * 16384 + tid * 16;                                \
    load_lds16(srcA[(H) * 2 + 0] + (size_t)(T) * 64, d_);                     \
    load_lds16(srcA[(H) * 2 + 1] + (size_t)(T) * 64, d_ + 8192); }
#define STB(ARR, T, H)                                                        \
  { char* d_ = (ARR) + (H) * 16384 + tid * 16;                                \
    load_lds16(srcB[(H) * 2 + 0] + (size_t)(T) * 64, d_);                     \
    load_lds16(srcB[(H) * 2 + 1] + (size_t)(T) * 64, d_ + 8192); }

  // ---- 32x32x16 fragment addressing ----
  // A-frag (mf, s): lane reads row r = wr*128 + mf*32 + (lane&31),
  //   16B chunk c = (2s + (lane>>5)) ^ (r&7)  [r&7 == lane&7]
  const int l31 = lane & 31, kh = lane >> 5, xr = lane & 7;
  int coff[4];
#pragma unroll
  for (int s = 0; s < 4; s++) coff[s] = (((s << 1) + kh) ^ xr) << 4;
  int offA[4];
#pragma unroll
  for (int mf = 0; mf < 4; mf++) offA[mf] = (((wr << 7) + (mf << 5) + l31) << 7);
  int offB[2];
#pragma unroll
  for (int nf = 0; nf < 2; nf++) offB[nf] = (((wc << 6) + (nf << 5) + l31) << 7);

  v16f acc[4][2] = {};
  v8s a[4][2], b[2][4];

#define R_AS(BASE, S0)                                                        \
  _Pragma("unroll") for (int mf = 0; mf < 4; mf++)                            \
  _Pragma("unroll") for (int ss = 0; ss < 2; ss++)                            \
    a[mf][ss] = *(const v8s*)((BASE) + offA[mf] + coff[(S0) + ss]);
#define R_BALL(BASE)                                                          \
  _Pragma("unroll") for (int nf = 0; nf < 2; nf++)                            \
  _Pragma("unroll") for (int s = 0; s < 4; s++)                               \
    b[nf][s] = *(const v8s*)((BASE) + offB[nf] + coff[s]);
#define MFMA_P(S0)                                                            \
  __builtin_amdgcn_s_setprio(1);                                              \
  _Pragma("unroll") for (int ss = 0; ss < 2; ss++)                            \
  _Pragma("unroll") for (int mf = 0; mf < 4; mf++)                            \
  _Pragma("unroll") for (int nf = 0; nf < 2; nf++)                            \
    acc[mf][nf] = __builtin_amdgcn_mfma_f32_32x32x16_bf16(                    \
        a[mf][ss], b[nf][(S0) + ss], acc[mf][nf], 0, 0, 0);                   \
  __builtin_amdgcn_s_setprio(0);

// One K-tile, 2 phases / 2 barriers. AR/BR read arrays; AN = other A array.
// P1: reads A(s0,s1)+B(all); stage A(T+1)->AN. BAR1 (B(T) reads all retired).
// MFMA s01. P2: reads A(s2,s3); stage B(T+2)->BR; gate; BAR2; MFMA s23.
#define BODY(AR, BR, AN, T)                                                   \
  {                                                                           \
    R_AS(AR, 0); R_BALL(BR);                                                  \
    STA(AN, (T) + 1, 0); STA(AN, (T) + 1, 1);                                 \
    BAR();                                                                    \
    MFMA_P(0);                                                                \
    R_AS(AR, 2);                                                              \
    STB(BR, (T) + 2, 0); STB(BR, (T) + 2, 1);                                 \
    if (DRAIN) { asm volatile("s_waitcnt vmcnt(0)" ::: "memory"); }           \
    else       { asm volatile("s_waitcnt vmcnt(4)" ::: "memory"); }           \
    BAR();                                                                    \
    MFMA_P(2);                                                                \
  }

  // ---- prologue: A(0)->A0, B(0)->B0, B(1)->B1; gate tile 0 ----
  STA(A0s, 0, 0); STA(A0s, 0, 1);
  STB(B0s, 0, 0); STB(B0s, 0, 1);
  STB(B1s, 1, 0); STB(B1s, 1, 1);
  asm volatile("s_waitcnt vmcnt(4)" ::: "memory");
  BAR();

  for (int t = 0; t < nt; t += 2) {
    BODY(A0s, B0s, A1s, t);
    BODY(A1s, B1s, A0s, t + 1);
  }
  asm volatile("s_waitcnt vmcnt(0) lgkmcnt(0)" ::: "memory");

  // ---- epilogue: C/D map col=lane&31, row=(reg&3)+8*(reg>>2)+4*(lane>>5) ----
  float bv[2];
#pragma unroll
  for (int nf = 0; nf < 2; nf++) bv[nf] = bp[n0 + (wc << 6) + (nf << 5) + l31];
#pragma unroll
  for (int mf = 0; mf < 4; mf++) {
#pragma unroll
    for (int reg = 0; reg < 16; reg++) {
      int gm = m0 + (wr << 7) + (mf << 5) + (reg & 3) + ((reg >> 2) << 3) + (kh << 2);
      int trow = 0; float sv = 0.f;
      if (MODE == 2) { trow = tok[gm]; sv = scr[gm]; }
#pragma unroll
      for (int nf = 0; nf < 2; nf++) {
        int gn = n0 + (wc << 6) + (nf << 5) + l31;
        float v = acc[mf][nf][reg] + bv[nf];
        if (MODE == 0)      outH[(size_t)gm * N + gn] = __float2bfloat16(gelu_tanh(v));
        else if (MODE == 1) outF[(size_t)gm * N + gn] = v;
        else                atomicAdd(outF + (size_t)trow * N + gn, v * sv);
      }
    }
  }
}

extern "C" void kernel_launch(void* const* d_in, const int* in_sizes, int n_in,
                              void* d_out, int out_size, void* d_ws, size_t ws_size,
                              hipStream_t stream) {
  const float* x   = (const float*)d_in[0];
  const float* gate= (const float*)d_in[1];
  const float* W1  = (const float*)d_in[2];
  const float* b1  = (const float*)d_in[3];
  const float* W2  = (const float*)d_in[4];
  const float* b2  = (const float*)d_in[5];
  const float* Ws1 = (const float*)d_in[6];
  const float* bs1 = (const float*)d_in[7];
  const float* Ws2 = (const float*)d_in[8];
  const float* bs2 = (const float*)d_in[9];
  float* out = (float*)d_out;

  char* w = (char*)d_ws;
  size_t off = 0;
  auto alloc = [&](size_t bytes) {
    void* p = w + off;
    off = (off + bytes + 255) & ~(size_t)255;
    return p;
  };
  bf16* xb    = (bf16*)alloc((size_t)NT * ND * 2);
  bf16* w1T   = (bf16*)alloc((size_t)NE * NH * ND * 2);
  bf16* w2T   = (bf16*)alloc((size_t)NE * ND * NH * 2);
  bf16* ws1T  = (bf16*)alloc((size_t)NH * ND * 2);
  bf16* ws2T  = (bf16*)alloc((size_t)ND * NH * 2);
  bf16* h     = (bf16*)alloc((size_t)NT * NH * 2);
  float* probs= (float*)alloc((size_t)NE * NT * 4);
  unsigned* thr = (unsigned*)alloc(NE * 4);
  int* needed = (int*)alloc(NE * 4);
  int* cnt    = (int*)alloc(2 * NE * 4);
  int* eqc    = cnt + NE;
  int* tok    = (int*)alloc((size_t)NE * CAP * 4);
  float* scr  = (float*)alloc((size_t)NE * CAP * 4);
  (void)alloc(65536);   // tail pad: GEMM over-stages up to 2 K-tiles harmlessly
  if (off > ws_size) return;

  // ---- precision conversion (+ weight transpose to N-major) ----
  cvt_bf16<<<2048, 256, 0, stream>>>(x, xb, NT * ND);
  tcvt<<<dim3(NH / 32, ND / 32, NE), 256, 0, stream>>>(W1, w1T, ND, NH);
  tcvt<<<dim3(ND / 32, NH / 32, NE), 256, 0, stream>>>(W2, w2T, NH, ND);
  tcvt<<<dim3(NH / 32, ND / 32, 1), 256, 0, stream>>>(Ws1, ws1T, ND, NH);
  tcvt<<<dim3(ND / 32, NH / 32, 1), 256, 0, stream>>>(Ws2, ws2T, NH, ND);

  // ---- router + top-k selection ----
  router_k<<<NT / 4, 256, 0, stream>>>(x, gate, probs);
  topk_k<<<NE, 1024, 0, stream>>>(probs, thr, needed);
  zero_counters<<<1, 64, 0, stream>>>(cnt);
  compact_k<<<NE * NT / 256, 256, 0, stream>>>(probs, thr, needed, cnt, eqc, tok, scr);

  // ---- shared expert (GEMM1: DRAIN=0 counted-vmcnt arm of the A/B) ----
  gemm256<0, 0><<<dim3(NH / 256, NT / 256), 512, 0, stream>>>(
      xb, ND, nullptr, ws1T, 0, 30, bs1, 0, NH, ND, h, nullptr, nullptr, nullptr);
  gemm256<1, 0><<<dim3(ND / 256, NT / 256), 512, 0, stream>>>(
      h, NH, nullptr, ws2T, 0, 30, bs2, 0, ND, NH, nullptr, out, nullptr, nullptr);

  // ---- routed experts (GEMM1: DRAIN=1 vmcnt(0) arm of the A/B) ----
  gemm256<0, 1><<<dim3(NH / 256, NT / 256), 512, 0, stream>>>(
      xb, ND, tok, w1T, (long long)NH * ND, 11, b1, NH, NH, ND, h, nullptr, nullptr, nullptr);
  gemm256<2, 0><<<dim3(ND / 256, NT / 256), 512, 0, stream>>>(
      h, NH, nullptr, w2T, (long long)ND * NH, 11, b2, ND, ND, NH, nullptr, out, tok, scr);
}

// Round 8
// 835.464 us; speedup vs baseline: 1.1901x; 1.1901x over previous
//
#include <hip/hip_runtime.h>
#include <hip/hip_bf16.h>

using bf16 = __hip_bfloat16;
typedef short v8s __attribute__((ext_vector_type(8)));
typedef float v4f __attribute__((ext_vector_type(4)));
typedef int v4i __attribute__((ext_vector_type(4)));

#define NE 8
#define NT 16384
#define ND 1024
#define NH 4096
#define CAP 2048

__device__ __forceinline__ void load_lds16(const void* g, void* s) {
  __builtin_amdgcn_global_load_lds(
      (const __attribute__((address_space(1))) unsigned int*)g,
      (__attribute__((address_space(3))) unsigned int*)s, 16, 0, 0);
}

__device__ __forceinline__ float gelu_tanh(float x) {
  float u = 0.7978845608028654f * (x + 0.044715f * x * x * x);
  float e = __expf(2.0f * u);
  float t = 1.0f - 2.0f / (e + 1.0f);
  return 0.5f * x * (1.0f + t);
}

// ---------------- fp32 -> bf16 elementwise ----------------
__global__ __launch_bounds__(256) void cvt_bf16(const float* __restrict__ s,
                                                bf16* __restrict__ d, int n) {
  for (int i = (blockIdx.x * 256 + threadIdx.x) * 4; i < n; i += gridDim.x * 1024) {
    float4 v = *(const float4*)(s + i);
    bf16 o[4];
    o[0] = __float2bfloat16(v.x); o[1] = __float2bfloat16(v.y);
    o[2] = __float2bfloat16(v.z); o[3] = __float2bfloat16(v.w);
    *(ushort4*)(d + i) = *(ushort4*)o;
  }
}

// ---------------- fp32 (R,C) -> bf16 (C,R), batched over blockIdx.z ----------
__global__ __launch_bounds__(256) void tcvt(const float* __restrict__ src,
                                            bf16* __restrict__ dst, int R, int C) {
  __shared__ float tile[32][33];
  size_t mo = (size_t)blockIdx.z * R * C;
  int c0 = blockIdx.x * 32, r0 = blockIdx.y * 32;
  int tx = threadIdx.x & 31, ty = threadIdx.x >> 5;
  for (int i = ty; i < 32; i += 8)
    tile[i][tx] = src[mo + (size_t)(r0 + i) * C + c0 + tx];
  __syncthreads();
  for (int i = ty; i < 32; i += 8)
    dst[mo + (size_t)(c0 + i) * R + r0 + tx] = __float2bfloat16(tile[tx][i]);
}

// ------- per-row int8 quantization of bf16 rows (len 1024): q + fp32 scale ---
__global__ __launch_bounds__(256) void rowq_k(const bf16* __restrict__ in,
                                              signed char* __restrict__ q,
                                              float* __restrict__ sc, int nrows) {
  int row = blockIdx.x * 4 + (threadIdx.x >> 6);
  if (row >= nrows) return;
  int lane = threadIdx.x & 63;
  const ushort* r = (const ushort*)in + (size_t)row * 1024;
  ushort4 u[4];
  u[0] = *(const ushort4*)(r + lane * 8);
  u[1] = *(const ushort4*)(r + lane * 8 + 4);
  u[2] = *(const ushort4*)(r + 512 + lane * 8);
  u[3] = *(const ushort4*)(r + 512 + lane * 8 + 4);
  float f[16];
#pragma unroll
  for (int j = 0; j < 4; j++) {
    f[j * 4 + 0] = __uint_as_float((unsigned)u[j].x << 16);
    f[j * 4 + 1] = __uint_as_float((unsigned)u[j].y << 16);
    f[j * 4 + 2] = __uint_as_float((unsigned)u[j].z << 16);
    f[j * 4 + 3] = __uint_as_float((unsigned)u[j].w << 16);
  }
  float m = 0.f;
#pragma unroll
  for (int j = 0; j < 16; j++) m = fmaxf(m, fabsf(f[j]));
#pragma unroll
  for (int off = 32; off > 0; off >>= 1) m = fmaxf(m, __shfl_xor(m, off));
  float inv = (m > 1e-30f) ? 127.0f / m : 0.0f;
  int b[16];
#pragma unroll
  for (int j = 0; j < 16; j++) b[j] = (int)rintf(f[j] * inv);
  int w[4];
#pragma unroll
  for (int j = 0; j < 4; j++)
    w[j] = (b[j * 4] & 255) | ((b[j * 4 + 1] & 255) << 8) |
           ((b[j * 4 + 2] & 255) << 16) | (b[j * 4 + 3] << 24);
  *(int2*)(q + (size_t)row * 1024 + lane * 8) = make_int2(w[0], w[1]);
  *(int2*)(q + (size_t)row * 1024 + 512 + lane * 8) = make_int2(w[2], w[3]);
  if (lane == 0) sc[row] = m * (1.0f / 127.0f);
}

// ---------------- router: logits (fp64 accum) + softmax -> probs[E][T] ------
__global__ __launch_bounds__(256) void router_k(const float* __restrict__ x,
                                                const float* __restrict__ gate,
                                                float* __restrict__ probs) {
  int wave = threadIdx.x >> 6, lane = threadIdx.x & 63;
  int t = blockIdx.x * 4 + wave;
  const float* xr = x + (size_t)t * ND;
  double acc[NE];
#pragma unroll
  for (int e = 0; e < NE; e++) acc[e] = 0.0;
  for (int d = lane; d < ND; d += 64) {
    double xv = (double)xr[d];
    const float* g = gate + d * NE;
#pragma unroll
    for (int e = 0; e < NE; e++) acc[e] += xv * (double)g[e];
  }
#pragma unroll
  for (int e = 0; e < NE; e++) {
    double v = acc[e];
#pragma unroll
    for (int off = 32; off > 0; off >>= 1) v += __shfl_xor(v, off);
    acc[e] = v;
  }
  if (lane == 0) {
    float l[NE], m = -1e30f;
#pragma unroll
    for (int e = 0; e < NE; e++) { l[e] = (float)acc[e]; m = fmaxf(m, l[e]); }
    float p[NE], s = 0.f;
#pragma unroll
    for (int e = 0; e < NE; e++) { p[e] = expf(l[e] - m); s += p[e]; }
#pragma unroll
    for (int e = 0; e < NE; e++) probs[e * NT + t] = p[e] / s;
  }
}

// ---------------- per-expert radix select (also zeroes compaction counters) --
__global__ __launch_bounds__(1024) void topk_k(const float* __restrict__ probs,
                                               unsigned* __restrict__ thr_key,
                                               int* __restrict__ needed,
                                               int* __restrict__ cnt) {
  int e = blockIdx.x;
  const float* p = probs + e * NT;
  __shared__ int hist[256];
  __shared__ unsigned s_pref;
  __shared__ int s_rank;
  unsigned prefix = 0;
  int rank = CAP;
  for (int rd = 0; rd < 4; rd++) {
    int shift = 24 - rd * 8;
    if (threadIdx.x < 256) hist[threadIdx.x] = 0;
    __syncthreads();
    unsigned mask = (rd == 0) ? 0u : (0xFFFFFFFFu << (shift + 8));
    for (int t = threadIdx.x; t < NT; t += 1024) {
      unsigned k = __float_as_uint(p[t]);
      if ((k & mask) == prefix) atomicAdd(&hist[(k >> shift) & 255], 1);
    }
    __syncthreads();
    if (threadIdx.x == 0) {
      int cum = 0, b = 255;
      for (;;) {
        int c = hist[b];
        if (cum + c >= rank || b == 0) break;
        cum += c; b--;
      }
      s_pref = prefix | ((unsigned)b << shift);
      s_rank = rank - cum;
    }
    __syncthreads();
    prefix = s_pref; rank = s_rank;
    __syncthreads();
  }
  if (threadIdx.x == 0) {
    thr_key[e] = prefix; needed[e] = rank;
    cnt[e] = 0; cnt[NE + e] = 0;
  }
}

// -------- compact: block-aggregated (1 atomic/class/block) ------------------
__global__ __launch_bounds__(256) void compact_k(const float* __restrict__ probs,
                                                 const unsigned* __restrict__ thr_key,
                                                 const int* __restrict__ needed,
                                                 int* __restrict__ cnt, int* __restrict__ eqc,
                                                 int* __restrict__ tok, float* __restrict__ scr) {
  int gid = blockIdx.x * 256 + threadIdx.x;
  int e = gid >> 14, t = gid & (NT - 1);
  float pv = probs[gid];
  unsigned k = __float_as_uint(pv);
  unsigned thr = thr_key[e];
  int nd = needed[e];
  bool gt = k > thr, eq = k == thr;
  unsigned long long mgt = __ballot(gt), meq = __ballot(eq);
  int lane = threadIdx.x & 63, wv = threadIdx.x >> 6;
  __shared__ int wcnt[2][4];
  __shared__ int base[2];
  if (lane == 0) { wcnt[0][wv] = __popcll(mgt); wcnt[1][wv] = __popcll(meq); }
  __syncthreads();
  if (threadIdx.x == 0) {
    int s0 = wcnt[0][0] + wcnt[0][1] + wcnt[0][2] + wcnt[0][3];
    int s1 = wcnt[1][0] + wcnt[1][1] + wcnt[1][2] + wcnt[1][3];
    base[0] = s0 ? atomicAdd(&cnt[e], s0) : 0;
    base[1] = s1 ? atomicAdd(&eqc[e], s1) : 0;
  }
  __syncthreads();
  unsigned long long lm = (1ull << lane) - 1ull;
  if (gt) {
    int p = __popcll(mgt & lm);
    for (int w = 0; w < wv; w++) p += wcnt[0][w];
    int slot = base[0] + p;
    tok[e * CAP + slot] = t; scr[e * CAP + slot] = pv;
  } else if (eq) {
    int q = base[1] + __popcll(meq & lm);
    for (int w = 0; w < wv; w++) q += wcnt[1][w];
    if (q < nd) {
      int slot = (CAP - nd) + q;
      tok[e * CAP + slot] = t; scr[e * CAP + slot] = pv;
    }
  }
}

// === 256x256 bf16 MFMA GEMM (R4 schedule: 2-phase-early reads, counted waits) =
#define BAR() __builtin_amdgcn_s_barrier()
#define SBAR0() __builtin_amdgcn_sched_barrier(0)

template <int MODE>
__global__ __launch_bounds__(512, 2) void gemm256(
    const bf16* __restrict__ A, int lda, const int* __restrict__ rowmap,
    const bf16* __restrict__ BT, long long bstride, int gshift,
    const float* __restrict__ bias, int bias_stride,
    int N, int K,
    bf16* __restrict__ outH, float* __restrict__ outF,
    const int* __restrict__ tok, const float* __restrict__ scr) {
  __shared__ __attribute__((aligned(16))) char lds[131072];
  const int tid = threadIdx.x;
  const int lane = tid & 63, wv = tid >> 6;
  const int wr = wv >> 2, wc = wv & 3;
  const int hw = blockIdx.y * gridDim.x + blockIdx.x;
  const int nwg = gridDim.x * gridDim.y;
  const int swz = (hw & 7) * (nwg >> 3) + (hw >> 3);
  const int m0 = (swz & 63) << 8;
  const int n0 = (swz >> 6) << 8;
  const int grp = m0 >> gshift;
  const bf16* Bp = BT + (size_t)grp * (size_t)bstride;
  const float* bp = bias + (size_t)grp * (size_t)bias_stride;
  const int nt = K >> 6;

  const int srow = tid >> 3;
  const int pc = tid & 7;
  const int gc = pc ^ (srow & 7);
  const bf16* srcA[4]; const bf16* srcB[4];
#pragma unroll
  for (int g = 0; g < 4; g++) {
    int am = m0 + g * 64 + srow;
    int ar = rowmap ? rowmap[am] : am;
    srcA[g] = A + (size_t)ar * lda + gc * 8;
    srcB[g] = Bp + (size_t)(n0 + g * 64 + srow) * K + gc * 8;
  }
  auto stageA = [&](int t, int h) {
    char* d = lds + ((t & 1) * 65536 + h * 16384) + tid * 16;
    load_lds16(srcA[h * 2 + 0] + (size_t)t * 64, d);
    load_lds16(srcA[h * 2 + 1] + (size_t)t * 64, d + 8192);
  };
  auto stageB = [&](int t, int h) {
    char* d = lds + ((t & 1) * 65536 + 32768 + h * 16384) + tid * 16;
    load_lds16(srcB[h * 2 + 0] + (size_t)t * 64, d);
    load_lds16(srcB[h * 2 + 1] + (size_t)t * 64, d + 8192);
  };

  const int fr = lane & 15, hi = lane >> 4;
  const int xr = fr & 7;
  const int cb0 = ((0 + hi) ^ xr) << 4;
  const int cb1 = ((4 + hi) ^ xr) << 4;
  const int arow = ((wr << 7) + fr) << 7;
  const int brow = ((wc << 6) + fr) << 7;

  v4f acc[8][4] = {};
  v8s a03[4][2], a47[4][2], b01[2][2], b23[2][2];

#define R_A03(BASE)                                                           \
  _Pragma("unroll") for (int mi = 0; mi < 4; mi++) {                          \
    a03[mi][0] = *(const v8s*)((BASE) + arow + mi * 2048 + cb0);              \
    a03[mi][1] = *(const v8s*)((BASE) + arow + mi * 2048 + cb1);              \
  }
#define R_A47(BASE)                                                           \
  _Pragma("unroll") for (int mi = 0; mi < 4; mi++) {                          \
    a47[mi][0] = *(const v8s*)((BASE) + arow + (4 + mi) * 2048 + cb0);        \
    a47[mi][1] = *(const v8s*)((BASE) + arow + (4 + mi) * 2048 + cb1);        \
  }
#define R_B01(BASE)                                                           \
  _Pragma("unroll") for (int ni = 0; ni < 2; ni++) {                          \
    b01[ni][0] = *(const v8s*)((BASE) + brow + ni * 2048 + cb0);              \
    b01[ni][1] = *(const v8s*)((BASE) + brow + ni * 2048 + cb1);              \
  }
#define R_B23(BASE)                                                           \
  _Pragma("unroll") for (int ni = 0; ni < 2; ni++) {                          \
    b23[ni][0] = *(const v8s*)((BASE) + brow + (2 + ni) * 2048 + cb0);        \
    b23[ni][1] = *(const v8s*)((BASE) + brow + (2 + ni) * 2048 + cb1);        \
  }
#define MFMA_Q(AB, BB, MOFF, NOFF)                                            \
  __builtin_amdgcn_s_setprio(1);                                              \
  _Pragma("unroll") for (int kk = 0; kk < 2; kk++)                            \
  _Pragma("unroll") for (int mi = 0; mi < 4; mi++)                            \
  _Pragma("unroll") for (int ni = 0; ni < 2; ni++)                            \
    acc[(MOFF) + mi][(NOFF) + ni] = __builtin_amdgcn_mfma_f32_16x16x32_bf16(  \
        AB[mi][kk], BB[ni][kk], acc[(MOFF) + mi][(NOFF) + ni], 0, 0, 0);      \
  __builtin_amdgcn_s_setprio(0);

  stageA(0, 0); stageA(0, 1); stageB(0, 0); stageB(0, 1);
  if (nt > 1) { stageB(1, 0); stageB(1, 1); }
  if (nt > 1) { asm volatile("s_waitcnt vmcnt(4)" ::: "memory"); }
  else        { asm volatile("s_waitcnt vmcnt(0)" ::: "memory"); }
  BAR();
  {
    const char* Ab0 = lds; const char* Bb0 = lds + 32768;
    R_A03(Ab0); R_B01(Bb0); R_B23(Bb0); R_A47(Ab0);
  }

  for (int t = 0; t < nt; ++t) {
    const char* AbN = lds + ((t + 1) & 1) * 65536;
    const char* BbN = AbN + 32768;
    asm volatile("s_waitcnt lgkmcnt(12)" ::: "memory"); SBAR0();
    MFMA_Q(a03, b01, 0, 0);
    if (t + 1 < nt) stageA(t + 1, 0);
    asm volatile("s_waitcnt lgkmcnt(8)" ::: "memory"); SBAR0();
    MFMA_Q(a03, b23, 0, 2);
    if (t + 1 < nt) stageA(t + 1, 1);
    BAR();
    asm volatile("s_waitcnt lgkmcnt(0)" ::: "memory"); SBAR0();
    MFMA_Q(a47, b01, 4, 0);
    if (t + 2 < nt) stageB(t + 2, 0);
    if (t + 2 < nt) stageB(t + 2, 1);
    if (t + 2 < nt) { asm volatile("s_waitcnt vmcnt(4)" ::: "memory"); }
    else            { asm volatile("s_waitcnt vmcnt(0)" ::: "memory"); }
    BAR();
    if (t + 1 < nt) { R_A03(AbN); R_B01(BbN); }
    MFMA_Q(a47, b23, 4, 2);
    if (t + 1 < nt) { R_B23(BbN); R_A47(AbN); }
  }
  asm volatile("s_waitcnt vmcnt(0) lgkmcnt(0)" ::: "memory");

  float bv[4];
#pragma unroll
  for (int ni = 0; ni < 4; ni++) bv[ni] = bp[n0 + (wc << 6) + ni * 16 + fr];
  const int rbase = m0 + (wr << 7) + (hi << 2);
#pragma unroll
  for (int mi = 0; mi < 8; mi++) {
#pragma unroll
    for (int r = 0; r < 4; r++) {
      int gm = rbase + mi * 16 + r;
      int trow = 0; float sv = 0.f;
      if (MODE == 2) { trow = tok[gm]; sv = scr[gm]; }
#pragma unroll
      for (int ni = 0; ni < 4; ni++) {
        int gn = n0 + (wc << 6) + ni * 16 + fr;
        float v = acc[mi][ni][r] + bv[ni];
        if (MODE == 0)      outH[(size_t)gm * N + gn] = __float2bfloat16(gelu_tanh(v));
        else if (MODE == 1) outF[(size_t)gm * N + gn] = v;
        else                atomicAdd(outF + (size_t)trow * N + gn, v * sv);
      }
    }
  }
}

// === int8 clone of the same schedule for the routed GEMM1 (K=1024, nt=8) =====
// LDS row = 128 B = K=128 i8; fragment/staging byte math identical to bf16.
__global__ __launch_bounds__(512, 2) void gemm256_q(
    const signed char* __restrict__ A, const int* __restrict__ rowmap,
    const signed char* __restrict__ BT,
    const float* __restrict__ sxr, const float* __restrict__ swc,
    const float* __restrict__ bias, bf16* __restrict__ outH) {
  __shared__ __attribute__((aligned(16))) char lds[131072];
  const int tid = threadIdx.x;
  const int lane = tid & 63, wv = tid >> 6;
  const int wr = wv >> 2, wc = wv & 3;
  const int m0 = blockIdx.y << 8, n0 = blockIdx.x << 8;
  const int grp = m0 >> 11;
  const signed char* Bp = BT + (size_t)grp * ((size_t)NH * ND);
  const float* bp = bias + grp * NH;
  const float* swp = swc + grp * NH;
  const int nt = ND >> 7;                       // 8

  const int srow = tid >> 3;
  const int pc = tid & 7;
  const int gc = pc ^ (srow & 7);
  const signed char* srcA[4]; const signed char* srcB[4];
#pragma unroll
  for (int g = 0; g < 4; g++) {
    int am = m0 + g * 64 + srow;
    int ar = rowmap[am];
    srcA[g] = A + (size_t)ar * ND + gc * 16;
    srcB[g] = Bp + (size_t)(n0 + g * 64 + srow) * ND + gc * 16;
  }
  auto stageA = [&](int t, int h) {
    char* d = lds + ((t & 1) * 65536 + h * 16384) + tid * 16;
    load_lds16(srcA[h * 2 + 0] + (size_t)t * 128, d);
    load_lds16(srcA[h * 2 + 1] + (size_t)t * 128, d + 8192);
  };
  auto stageB = [&](int t, int h) {
    char* d = lds + ((t & 1) * 65536 + 32768 + h * 16384) + tid * 16;
    load_lds16(srcB[h * 2 + 0] + (size_t)t * 128, d);
    load_lds16(srcB[h * 2 + 1] + (size_t)t * 128, d + 8192);
  };

  const int fr = lane & 15, hi = lane >> 4;
  const int xr = fr & 7;
  const int cb0 = ((0 + hi) ^ xr) << 4;
  const int cb1 = ((4 + hi) ^ xr) << 4;
  const int arow = ((wr << 7) + fr) << 7;
  const int brow = ((wc << 6) + fr) << 7;

  v4i acc[8][4] = {};
  v4i a03[4][2], a47[4][2], b01[2][2], b23[2][2];

#define QR_A03(BASE)                                                          \
  _Pragma("unroll") for (int mi = 0; mi < 4; mi++) {                          \
    a03[mi][0] = *(const v4i*)((BASE) + arow + mi * 2048 + cb0);              \
    a03[mi][1] = *(const v4i*)((BASE) + arow + mi * 2048 + cb1);              \
  }
#define QR_A47(BASE)                                                          \
  _Pragma("unroll") for (int mi = 0; mi < 4; mi++) {                          \
    a47[mi][0] = *(const v4i*)((BASE) + arow + (4 + mi) * 2048 + cb0);        \
    a47[mi][1] = *(const v4i*)((BASE) + arow + (4 + mi) * 2048 + cb1);        \
  }
#define QR_B01(BASE)                                                          \
  _Pragma("unroll") for (int ni = 0; ni < 2; ni++) {                          \
    b01[ni][0] = *(const v4i*)((BASE) + brow + ni * 2048 + cb0);              \
    b01[ni][1] = *(const v4i*)((BASE) + brow + ni * 2048 + cb1);              \
  }
#define QR_B23(BASE)                                                          \
  _Pragma("unroll") for (int ni = 0; ni < 2; ni++) {                          \
    b23[ni][0] = *(const v4i*)((BASE) + brow + (2 + ni) * 2048 + cb0);        \
    b23[ni][1] = *(const v4i*)((BASE) + brow + (2 + ni) * 2048 + cb1);        \
  }
#define QMFMA_Q(AB, BB, MOFF, NOFF)                                           \
  __builtin_amdgcn_s_setprio(1);                                              \
  _Pragma("unroll") for (int kk = 0; kk < 2; kk++)                            \
  _Pragma("unroll") for (int mi = 0; mi < 4; mi++)                            \
  _Pragma("unroll") for (int ni = 0; ni < 2; ni++)                            \
    acc[(MOFF) + mi][(NOFF) + ni] = __builtin_amdgcn_mfma_i32_16x16x64_i8(    \
        AB[mi][kk], BB[ni][kk], acc[(MOFF) + mi][(NOFF) + ni], 0, 0, 0);      \
  __builtin_amdgcn_s_setprio(0);

  stageA(0, 0); stageA(0, 1); stageB(0, 0); stageB(0, 1);
  stageB(1, 0); stageB(1, 1);
  asm volatile("s_waitcnt vmcnt(4)" ::: "memory");
  BAR();
  {
    const char* Ab0 = lds; const char* Bb0 = lds + 32768;
    QR_A03(Ab0); QR_B01(Bb0); QR_B23(Bb0); QR_A47(Ab0);
  }

  for (int t = 0; t < nt; ++t) {
    const char* AbN = lds + ((t + 1) & 1) * 65536;
    const char* BbN = AbN + 32768;
    asm volatile("s_waitcnt lgkmcnt(12)" ::: "memory"); SBAR0();
    QMFMA_Q(a03, b01, 0, 0);
    if (t + 1 < nt) stageA(t + 1, 0);
    asm volatile("s_waitcnt lgkmcnt(8)" ::: "memory"); SBAR0();
    QMFMA_Q(a03, b23, 0, 2);
    if (t + 1 < nt) stageA(t + 1, 1);
    BAR();
    asm volatile("s_waitcnt lgkmcnt(0)" ::: "memory"); SBAR0();
    QMFMA_Q(a47, b01, 4, 0);
    if (t + 2 < nt) stageB(t + 2, 0);
    if (t + 2 < nt) stageB(t + 2, 1);
    if (t + 2 < nt) { asm volatile("s_waitcnt vmcnt(4)" ::: "memory"); }
    else            { asm volatile("s_waitcnt vmcnt(0)" ::: "memory"); }
    BAR();
    if (t + 1 < nt) { QR_A03(AbN); QR_B01(BbN); }
    QMFMA_Q(a47, b23, 4, 2);
    if (t + 1 < nt) { QR_B23(BbN); QR_A47(AbN); }
  }
  asm volatile("s_waitcnt vmcnt(0) lgkmcnt(0)" ::: "memory");

  float bv[4], swv[4];
#pragma unroll
  for (int ni = 0; ni < 4; ni++) {
    int gn = n0 + (wc << 6) + ni * 16 + fr;
    bv[ni] = bp[gn]; swv[ni] = swp[gn];
  }
  const int rbase = m0 + (wr << 7) + (hi << 2);
#pragma unroll
  for (int mi = 0; mi < 8; mi++) {
#pragma unroll
    for (int r = 0; r < 4; r++) {
      int gm = rbase + mi * 16 + r;
      float sxa = sxr[rowmap[gm]];
#pragma unroll
      for (int ni = 0; ni < 4; ni++) {
        int gn = n0 + (wc << 6) + ni * 16 + fr;
        float v = (float)acc[mi][ni][r] * (sxa * swv[ni]) + bv[ni];
        outH[(size_t)gm * NH + gn] = __float2bfloat16(gelu_tanh(v));
      }
    }
  }
}

extern "C" void kernel_launch(void* const* d_in, const int* in_sizes, int n_in,
                              void* d_out, int out_size, void* d_ws, size_t ws_size,
                              hipStream_t stream) {
  const float* x   = (const float*)d_in[0];
  const float* gate= (const float*)d_in[1];
  const float* W1  = (const float*)d_in[2];
  const float* b1  = (const float*)d_in[3];
  const float* W2  = (const float*)d_in[4];
  const float* b2  = (const float*)d_in[5];
  const float* Ws1 = (const float*)d_in[6];
  const float* bs1 = (const float*)d_in[7];
  const float* Ws2 = (const float*)d_in[8];
  const float* bs2 = (const float*)d_in[9];
  float* out = (float*)d_out;

  char* w = (char*)d_ws;
  size_t off = 0;
  auto alloc = [&](size_t bytes) {
    void* p = w + off;
    off = (off + bytes + 255) & ~(size_t)255;
    return p;
  };
  bf16* xb    = (bf16*)alloc((size_t)NT * ND * 2);
  bf16* w1T   = (bf16*)alloc((size_t)NE * NH * ND * 2);
  bf16* w2T   = (bf16*)alloc((size_t)NE * ND * NH * 2);
  bf16* ws1T  = (bf16*)alloc((size_t)NH * ND * 2);
  bf16* ws2T  = (bf16*)alloc((size_t)ND * NH * 2);
  bf16* h     = (bf16*)alloc((size_t)NT * NH * 2);
  signed char* xq  = (signed char*)alloc((size_t)NT * ND);
  signed char* w1q = (signed char*)alloc((size_t)NE * NH * ND);
  float* sx   = (float*)alloc((size_t)NT * 4);
  float* sw1  = (float*)alloc((size_t)NE * NH * 4);
  float* probs= (float*)alloc((size_t)NE * NT * 4);
  unsigned* thr = (unsigned*)alloc(NE * 4);
  int* needed = (int*)alloc(NE * 4);
  int* cnt    = (int*)alloc(2 * NE * 4);
  int* eqc    = cnt + NE;
  int* tok    = (int*)alloc((size_t)NE * CAP * 4);
  float* scr  = (float*)alloc((size_t)NE * CAP * 4);
  (void)alloc(65536);
  if (off > ws_size) return;

  // ---- precision conversion (+ weight transpose to N-major) ----
  cvt_bf16<<<2048, 256, 0, stream>>>(x, xb, NT * ND);
  tcvt<<<dim3(NH / 32, ND / 32, NE), 256, 0, stream>>>(W1, w1T, ND, NH);
  tcvt<<<dim3(ND / 32, NH / 32, NE), 256, 0, stream>>>(W2, w2T, NH, ND);
  tcvt<<<dim3(NH / 32, ND / 32, 1), 256, 0, stream>>>(Ws1, ws1T, ND, NH);
  tcvt<<<dim3(ND / 32, NH / 32, 1), 256, 0, stream>>>(Ws2, ws2T, NH, ND);

  // ---- int8 quantization (x rows; routed W1 rows) ----
  rowq_k<<<NT / 4, 256, 0, stream>>>(xb, xq, sx, NT);
  rowq_k<<<NE * NH / 4, 256, 0, stream>>>(w1T, w1q, sw1, NE * NH);

  // ---- router + top-k selection ----
  router_k<<<NT / 4, 256, 0, stream>>>(x, gate, probs);
  topk_k<<<NE, 1024, 0, stream>>>(probs, thr, needed, cnt);
  compact_k<<<NE * NT / 256, 256, 0, stream>>>(probs, thr, needed, cnt, eqc, tok, scr);

  // ---- shared expert (bf16) ----
  gemm256<0><<<dim3(NH / 256, NT / 256), 512, 0, stream>>>(
      xb, ND, nullptr, ws1T, 0, 30, bs1, 0, NH, ND, h, nullptr, nullptr, nullptr);
  gemm256<1><<<dim3(ND / 256, NT / 256), 512, 0, stream>>>(
      h, NH, nullptr, ws2T, 0, 30, bs2, 0, ND, NH, nullptr, out, nullptr, nullptr);

  // ---- routed experts: GEMM1 in int8, GEMM2 bf16 scatter-add ----
  gemm256_q<<<dim3(NH / 256, NT / 256), 512, 0, stream>>>(
      xq, tok, w1q, sx, sw1, b1, h);
  gemm256<2><<<dim3(ND / 256, NT / 256), 512, 0, stream>>>(
      h, NH, nullptr, w2T, (long long)ND * NH, 11, b2, ND, ND, NH, nullptr, out, tok, scr);
}